// Round 14
// baseline (144.515 us; speedup 1.0000x reference)
//
#include <hip/hip_runtime.h>
#include <math.h>

// out[d] = s_ho*h_o[d] + s_h*h[d]; per-token scalars from 6 dot-reductions.
// ZERO-COUPLING structure: one wave per token (lane owns 32 dims), so there
// is NO cross-wave reduction and NO per-token barrier at all. Tables (w
// pre-folded: wfaT[c][d] = w[d]*fa[d][c+1], wfb[d] = w[d]*fb[d]) live in LDS
// (40KB/block, transposed so lane stride = 16B -> full-bank b128 reads),
// filled once per block with a single lgkmcnt-only barrier amortized over 16
// tokens. Waves then stream their 4 tokens fully independently - the
// copy-ubench pattern that sustains 6.3 TB/s - with DPP reduce + readlane
// for the wave-uniform scalars.

constexpr int D    = 2048;
constexpr int RATE = 4;
constexpr float EPS = 1e-5f;
constexpr int NT   = 256;   // 4 waves/block
constexpr int T    = 4;     // tokens per wave; block covers 16 tokens

__device__ __forceinline__ float fast_tanh(float x) {
    const float e = __expf(2.0f * x);
    return 1.0f - 2.0f / (e + 1.0f);
}

template<int CTRL>
__device__ __forceinline__ float dpp_add(float x) {
    int m = __builtin_amdgcn_update_dpp(0, __float_as_int(x), CTRL, 0xf, 0xf, true);
    return x + __int_as_float(m);
}

// After this, lane 63 holds the 64-lane sum.
__device__ __forceinline__ float wave_sum_lane63(float x) {
    x = dpp_add<0x111>(x);  // row_shr:1
    x = dpp_add<0x112>(x);  // row_shr:2
    x = dpp_add<0x114>(x);  // row_shr:4
    x = dpp_add<0x118>(x);  // row_shr:8
    x = dpp_add<0x142>(x);  // row_bcast:15
    x = dpp_add<0x143>(x);  // row_bcast:31
    return x;
}

__device__ __forceinline__ float bcast63(float x) {
    return __int_as_float(__builtin_amdgcn_readlane(__float_as_int(x), 63));
}

// LDS-only block sync (no vmcnt drain): token-0 h loads stay in flight.
__device__ __forceinline__ void lds_barrier() {
    asm volatile("s_waitcnt lgkmcnt(0)" ::: "memory");
    __builtin_amdgcn_s_barrier();
    __builtin_amdgcn_sched_barrier(0);
}

__global__ __launch_bounds__(NT) void hyperconn_kernel(
    const float* __restrict__ h,
    const float* __restrict__ h_o,
    const float* __restrict__ sa,    // [4][5]
    const float* __restrict__ sb,    // [4]
    const float* __restrict__ fa,    // [2048][5]
    const float* __restrict__ a_sc,  // [1]
    const float* __restrict__ fb,    // [2048]
    const float* __restrict__ b_sc,  // [1]
    const float* __restrict__ w,     // [2048]
    float* __restrict__ out)
{
    const int tid  = threadIdx.x;          // 0..255
    const int wave = tid >> 6;             // 0..3
    const int lane = tid & 63;
    const int l4   = lane * 4;

    // wave's 4 consecutive tokens
    const size_t tw = (size_t)blockIdx.x * (4 * T) + wave * T;

    // ---- issue token 0's h loads immediately (hidden under table fill)
    float4 hv[8];
    #pragma unroll
    for (int j = 0; j < 8; ++j)
        hv[j] = *reinterpret_cast<const float4*>(h + tw * D + j * 256 + l4);

    // ---- LDS tables: wfaT[4][2048] + wfb[2048] = 40KB
    __shared__ float tabs[4 * D + D];

    {   // fill: thread handles dims [tid*8, tid*8+8)
        const int dd = tid * 8;
        float fr[40];
        #pragma unroll
        for (int q = 0; q < 10; ++q) {
            float4 t = *reinterpret_cast<const float4*>(fa + (size_t)dd * 5 + q * 4);
            fr[q*4+0]=t.x; fr[q*4+1]=t.y; fr[q*4+2]=t.z; fr[q*4+3]=t.w;
        }
        const float4 w0 = *reinterpret_cast<const float4*>(w + dd);
        const float4 w1 = *reinterpret_cast<const float4*>(w + dd + 4);
        const float4 f0 = *reinterpret_cast<const float4*>(fb + dd);
        const float4 f1 = *reinterpret_cast<const float4*>(fb + dd + 4);
        const float ww[8] = {w0.x,w0.y,w0.z,w0.w,w1.x,w1.y,w1.z,w1.w};
        const float ff[8] = {f0.x,f0.y,f0.z,f0.w,f1.x,f1.y,f1.z,f1.w};
        #pragma unroll
        for (int c = 0; c < 4; ++c) {
            float4 v0, v1;
            v0.x = ww[0]*fr[0*5+1+c]; v0.y = ww[1]*fr[1*5+1+c];
            v0.z = ww[2]*fr[2*5+1+c]; v0.w = ww[3]*fr[3*5+1+c];
            v1.x = ww[4]*fr[4*5+1+c]; v1.y = ww[5]*fr[5*5+1+c];
            v1.z = ww[6]*fr[6*5+1+c]; v1.w = ww[7]*fr[7*5+1+c];
            *reinterpret_cast<float4*>(&tabs[c * D + dd])     = v0;
            *reinterpret_cast<float4*>(&tabs[c * D + dd + 4]) = v1;
        }
        float4 b0, b1;
        b0.x = ww[0]*ff[0]; b0.y = ww[1]*ff[1]; b0.z = ww[2]*ff[2]; b0.w = ww[3]*ff[3];
        b1.x = ww[4]*ff[4]; b1.y = ww[5]*ff[5]; b1.z = ww[6]*ff[6]; b1.w = ww[7]*ff[7];
        *reinterpret_cast<float4*>(&tabs[4 * D + dd])     = b0;
        *reinterpret_cast<float4*>(&tabs[4 * D + dd + 4]) = b1;
    }

    // ---- uniform scalars
    const float a4 = a_sc[0] * (float)RATE;
    const float b4 = b_sc[0] * (float)RATE;
    float cs = 0.f;
    #pragma unroll
    for (int r = 0; r < RATE; ++r)
        #pragma unroll
        for (int c = 1; c <= RATE; ++c)
            cs += sa[r * (RATE + 1) + c];
    const float sbsum = sb[0] + sb[1] + sb[2] + sb[3];

    lds_barrier();   // h-token-0 loads remain in flight

    // ---- fully independent per-wave token loop: no syncs of any kind
    #pragma unroll
    for (int i = 0; i < T; ++i) {
        const size_t base = (tw + i) * D;

        if (i > 0) {   // token i's h loads (token 0 preloaded above)
            #pragma unroll
            for (int j = 0; j < 8; ++j)
                hv[j] = *reinterpret_cast<const float4*>(h + base + j * 256 + l4);
        }
        // h_o loads issued now; consumed ~1000 cycles later
        float4 ov[8];
        #pragma unroll
        for (int j = 0; j < 8; ++j)
            ov[j] = *reinterpret_cast<const float4*>(h_o + base + j * 256 + l4);

        float acc[6] = {0.f, 0.f, 0.f, 0.f, 0.f, 0.f};
        #pragma unroll
        for (int j = 0; j < 8; ++j) {
            const float4 hq = hv[j];
            const int o = j * 256 + l4;
            const float4 a0 = *reinterpret_cast<const float4*>(&tabs[0 * D + o]);
            const float4 a1 = *reinterpret_cast<const float4*>(&tabs[1 * D + o]);
            const float4 a2 = *reinterpret_cast<const float4*>(&tabs[2 * D + o]);
            const float4 a3 = *reinterpret_cast<const float4*>(&tabs[3 * D + o]);
            const float4 bq = *reinterpret_cast<const float4*>(&tabs[4 * D + o]);
            acc[0] = fmaf(hq.x,hq.x,fmaf(hq.y,hq.y,fmaf(hq.z,hq.z,fmaf(hq.w,hq.w,acc[0]))));
            acc[1] = fmaf(hq.x,a0.x,fmaf(hq.y,a0.y,fmaf(hq.z,a0.z,fmaf(hq.w,a0.w,acc[1]))));
            acc[2] = fmaf(hq.x,a1.x,fmaf(hq.y,a1.y,fmaf(hq.z,a1.z,fmaf(hq.w,a1.w,acc[2]))));
            acc[3] = fmaf(hq.x,a2.x,fmaf(hq.y,a2.y,fmaf(hq.z,a2.z,fmaf(hq.w,a2.w,acc[3]))));
            acc[4] = fmaf(hq.x,a3.x,fmaf(hq.y,a3.y,fmaf(hq.z,a3.z,fmaf(hq.w,a3.w,acc[4]))));
            acc[5] = fmaf(hq.x,bq.x,fmaf(hq.y,bq.y,fmaf(hq.z,bq.z,fmaf(hq.w,bq.w,acc[5]))));
        }

        #pragma unroll
        for (int k = 0; k < 6; ++k) acc[k] = wave_sum_lane63(acc[k]);
        const float tot0 = bcast63(acc[0]);
        const float tot1 = bcast63(acc[1]);
        const float tot2 = bcast63(acc[2]);
        const float tot3 = bcast63(acc[3]);
        const float tot4 = bcast63(acc[4]);
        const float tot5 = bcast63(acc[5]);

        const float rms  = rsqrtf(tot0 * (1.0f / (float)D) + EPS);
        const float s_h  = a4 * (fast_tanh(tot1 * rms) + fast_tanh(tot2 * rms) +
                                 fast_tanh(tot3 * rms) + fast_tanh(tot4 * rms)) + cs;
        const float s_ho = b4 * fast_tanh(tot5 * rms) + sbsum;

        #pragma unroll
        for (int j = 0; j < 8; ++j) {
            const float4 hq = hv[j];
            const float4 oq = ov[j];
            float4 r;
            r.x = fmaf(s_ho, oq.x, s_h * hq.x);
            r.y = fmaf(s_ho, oq.y, s_h * hq.y);
            r.z = fmaf(s_ho, oq.z, s_h * hq.z);
            r.w = fmaf(s_ho, oq.w, s_h * hq.w);
            *reinterpret_cast<float4*>(out + base + j * 256 + l4) = r;
        }
    }
}

extern "C" void kernel_launch(void* const* d_in, const int* in_sizes, int n_in,
                              void* d_out, int out_size, void* d_ws, size_t ws_size,
                              hipStream_t stream) {
    const float* h    = (const float*)d_in[0];
    const float* h_o  = (const float*)d_in[1];
    const float* sa   = (const float*)d_in[2];
    const float* sb   = (const float*)d_in[3];
    const float* fa   = (const float*)d_in[4];
    const float* a_sc = (const float*)d_in[5];
    const float* fb   = (const float*)d_in[6];
    const float* b_sc = (const float*)d_in[7];
    const float* w    = (const float*)d_in[8];
    float* out = (float*)d_out;

    const int ntok   = in_sizes[0] / D;       // B*L = 16384
    const int blocks = ntok / (4 * T);        // 1024
    hyperconn_kernel<<<blocks, NT, 0, stream>>>(h, h_o, sa, sb, fa, a_sc, fb, b_sc, w, out);
}

// Round 15
// 77.552 us; speedup vs baseline: 1.8635x; 1.8635x over previous
//
#include <hip/hip_runtime.h>
#include <math.h>

// out[d] = s_ho*h_o[d] + s_h*h[d]; per-token scalars from 6 dot-reductions.
// R12 structure with the occupancy variable finally isolated: TPB=4 (hA = 16
// VGPR), w prefolded into fa/fb tables (20 VGPR, saves wv + 1 mul/dim), and
// __launch_bounds__(512,8) pinning VGPR <= 64 so all 8 waves/SIMD can be
// resident (m69: waves halve at 64/128/256). Traffic stays minimal (h read
// once into regs, h_o once, out once). lgkm-only barriers as in R13.

constexpr int D    = 2048;
constexpr int RATE = 4;
constexpr float EPS = 1e-5f;
constexpr int TPB  = 4;    // tokens per block
constexpr int NT   = 512;  // threads; lane owns D/NT = 4 dims

__device__ __forceinline__ float fast_tanh(float x) {
    const float e = __expf(2.0f * x);
    return 1.0f - 2.0f / (e + 1.0f);
}

template<int CTRL>
__device__ __forceinline__ float dpp_add(float x) {
    int m = __builtin_amdgcn_update_dpp(0, __float_as_int(x), CTRL, 0xf, 0xf, true);
    return x + __int_as_float(m);
}

// After this, lane 63 holds the 64-lane sum.
__device__ __forceinline__ float wave_sum_lane63(float x) {
    x = dpp_add<0x111>(x);  // row_shr:1
    x = dpp_add<0x112>(x);  // row_shr:2
    x = dpp_add<0x114>(x);  // row_shr:4
    x = dpp_add<0x118>(x);  // row_shr:8
    x = dpp_add<0x142>(x);  // row_bcast:15
    x = dpp_add<0x143>(x);  // row_bcast:31
    return x;
}

// LDS-only block sync: no vmcnt(0) drain, outstanding global loads survive.
__device__ __forceinline__ void lds_barrier() {
    asm volatile("s_waitcnt lgkmcnt(0)" ::: "memory");
    __builtin_amdgcn_s_barrier();
    __builtin_amdgcn_sched_barrier(0);
}

__global__ __launch_bounds__(NT, 8) void hyperconn_kernel(
    const float* __restrict__ h,
    const float* __restrict__ h_o,
    const float* __restrict__ sa,    // [4][5]
    const float* __restrict__ sb,    // [4]
    const float* __restrict__ fa,    // [2048][5]
    const float* __restrict__ a_sc,  // [1]
    const float* __restrict__ fb,    // [2048]
    const float* __restrict__ b_sc,  // [1]
    const float* __restrict__ w,     // [2048]
    float* __restrict__ out)
{
    const int tid  = threadIdx.x;          // 0..511
    const int d0   = tid * 4;
    const int wave = tid >> 6;             // 0..7
    const int lane = tid & 63;
    const size_t t0 = (size_t)blockIdx.x * TPB;

    // ---- h for the block's 4 tokens -> registers (16 VGPR), issued first
    float4 hA[TPB];
    #pragma unroll
    for (int i = 0; i < TPB; ++i)
        hA[i] = *reinterpret_cast<const float4*>(h + (t0 + i) * D + d0);

    // ---- prefolded tables: wfa_c[j] = w*fa[.][c+1], wfb[j] = w*fb  (20 VGPR)
    float fav[16], fbv[4];
    {
        const float4 wq = *reinterpret_cast<const float4*>(w + d0);
        const float ww[4] = {wq.x, wq.y, wq.z, wq.w};
        float tmp[20];
        #pragma unroll
        for (int q = 0; q < 5; ++q) {
            float4 t = *reinterpret_cast<const float4*>(fa + (size_t)d0 * 5 + q * 4);
            tmp[q*4+0]=t.x; tmp[q*4+1]=t.y; tmp[q*4+2]=t.z; tmp[q*4+3]=t.w;
        }
        #pragma unroll
        for (int j = 0; j < 4; ++j)
            #pragma unroll
            for (int c = 0; c < 4; ++c)
                fav[j*4+c] = ww[j] * tmp[j*5 + 1 + c];
        const float4 fq = *reinterpret_cast<const float4*>(fb + d0);
        fbv[0] = ww[0]*fq.x; fbv[1] = ww[1]*fq.y;
        fbv[2] = ww[2]*fq.z; fbv[3] = ww[3]*fq.w;
    }

    const float a4 = a_sc[0] * (float)RATE;
    const float b4 = b_sc[0] * (float)RATE;
    float cs = 0.f;
    #pragma unroll
    for (int r = 0; r < RATE; ++r)
        #pragma unroll
        for (int c = 1; c <= RATE; ++c)
            cs += sa[r * (RATE + 1) + c];
    const float sbsum = sb[0] + sb[1] + sb[2] + sb[3];

    __shared__ float  red[TPB][48];   // [token][wave*6+k]
    __shared__ float2 s2[TPB];        // (s_h, s_ho) per token

    // ---- phase 1: per-token partials + DPP reduce (no syncs inside)
    #pragma unroll
    for (int i = 0; i < TPB; ++i) {
        const float hv[4] = {hA[i].x, hA[i].y, hA[i].z, hA[i].w};
        float acc[6] = {0.f, 0.f, 0.f, 0.f, 0.f, 0.f};
        #pragma unroll
        for (int j = 0; j < 4; ++j) {
            const float x = hv[j];
            acc[0] = fmaf(x, x,          acc[0]);
            acc[1] = fmaf(x, fav[j*4+0], acc[1]);
            acc[2] = fmaf(x, fav[j*4+1], acc[2]);
            acc[3] = fmaf(x, fav[j*4+2], acc[3]);
            acc[4] = fmaf(x, fav[j*4+3], acc[4]);
            acc[5] = fmaf(x, fbv[j],     acc[5]);
        }
        #pragma unroll
        for (int k = 0; k < 6; ++k) acc[k] = wave_sum_lane63(acc[k]);
        if (lane == 63) {
            #pragma unroll
            for (int k = 0; k < 6; ++k) red[i][wave * 6 + k] = acc[k];
        }
    }

    lds_barrier();

    // ---- finalize: wave i (i<TPB) handles token i
    if (wave < TPB) {
        const int i = wave;
        float tot[6] = {0.f, 0.f, 0.f, 0.f, 0.f, 0.f};
        #pragma unroll
        for (int v = 0; v < 8; ++v)
            #pragma unroll
            for (int k = 0; k < 6; ++k)
                tot[k] += red[i][v * 6 + k];
        const float rms  = rsqrtf(tot[0] * (1.0f / (float)D) + EPS);
        const float s_h  = a4 * (fast_tanh(tot[1] * rms) + fast_tanh(tot[2] * rms) +
                                 fast_tanh(tot[3] * rms) + fast_tanh(tot[4] * rms)) + cs;
        const float s_ho = b4 * fast_tanh(tot[5] * rms) + sbsum;
        if (lane == 0) s2[i] = make_float2(s_h, s_ho);
    }

    lds_barrier();

    // ---- phase 2: h_o stream + fma + store; h already in registers
    #pragma unroll
    for (int i = 0; i < TPB; ++i) {
        const float2 s = s2[i];
        const size_t base = (t0 + i) * D + d0;
        const float4 oq = *reinterpret_cast<const float4*>(h_o + base);
        float4 r;
        r.x = fmaf(s.y, oq.x, s.x * hA[i].x);
        r.y = fmaf(s.y, oq.y, s.x * hA[i].y);
        r.z = fmaf(s.y, oq.z, s.x * hA[i].z);
        r.w = fmaf(s.y, oq.w, s.x * hA[i].w);
        *reinterpret_cast<float4*>(out + base) = r;
    }
}

extern "C" void kernel_launch(void* const* d_in, const int* in_sizes, int n_in,
                              void* d_out, int out_size, void* d_ws, size_t ws_size,
                              hipStream_t stream) {
    const float* h    = (const float*)d_in[0];
    const float* h_o  = (const float*)d_in[1];
    const float* sa   = (const float*)d_in[2];
    const float* sb   = (const float*)d_in[3];
    const float* fa   = (const float*)d_in[4];
    const float* a_sc = (const float*)d_in[5];
    const float* fb   = (const float*)d_in[6];
    const float* b_sc = (const float*)d_in[7];
    const float* w    = (const float*)d_in[8];
    float* out = (float*)d_out;

    const int ntok   = in_sizes[0] / D;       // B*L = 16384
    const int blocks = ntok / TPB;            // 4096
    hyperconn_kernel<<<blocks, NT, 0, stream>>>(h, h_o, sa, sb, fa, a_sc, fb, b_sc, w, out);
}